// Round 3
// baseline (169.817 us; speedup 1.0000x reference)
//
#include <hip/hip_runtime.h>

// PointPillarScatter3d: scatter-mean of pillar features into BEV grid.
// R3: tile-binned gather with LDS-staged transpose.
//   - fill: bin points into per-tile (64-cell) lists
//   - gather: coalesced feature reads (lanes=channel) -> LDS accumulate ->
//             coalesced float4 output writes (lanes=spatial)
// inputs: d_in[0] = pillar_features [N,C] fp32, d_in[1] = voxel_coords [N,4] int32 (b,z,y,x)
// output: bev [B, C, NY, NX] fp32.

constexpr int NXc = 360;
constexpr int NYc = 360;
constexpr int NZc = 1;
constexpr int Cc  = 128;
constexpr int Bc  = 4;
constexpr int Sc  = NZc * NYc * NXc;     // 129600 (divisible by 64)
constexpr int BSc = Bc * Sc;             // 518400
constexpr int TILE  = 64;                // cells per tile
constexpr int NTILE = BSc / TILE;        // 8100
constexpr int TCAP  = 96;                // max points/tile (mean 19.75, Poisson tail ~0)
constexpr int LPAD  = Cc + 1;            // padded LDS row stride (bank-conflict-free)

// ---- fill: bin points into tiles -------------------------------------------
__global__ void pps_fill_tiles(const int* __restrict__ coords,
                               int* __restrict__ tile_cnt,
                               int* __restrict__ tile_list, int N) {
    int i = blockIdx.x * blockDim.x + threadIdx.x;
    if (i >= N) return;
    int4 c = reinterpret_cast<const int4*>(coords)[i];          // (b,z,y,x)
    int gidx = c.x * Sc + c.y * (NYc * NXc) + c.z * NXc + c.w;  // 0..BSc-1
    int tile = gidx >> 6;                                       // TILE=64
    int cell = gidx & 63;
    int slot = atomicAdd(&tile_cnt[tile], 1);
    if (slot < TCAP) tile_list[tile * TCAP + slot] = (i << 6) | cell;
}

// ---- gather: one block per 64-cell tile ------------------------------------
__global__ __launch_bounds__(256)
void pps_gather2(const float* __restrict__ feat,
                 const int* __restrict__ tile_cnt,
                 const int* __restrict__ tile_list,
                 float* __restrict__ out) {
    __shared__ float lsum[TILE * LPAD];   // 33 KB accumulation tile
    __shared__ float linv[TILE];
    __shared__ int   lcnt[TILE];
    __shared__ int   slist[TCAP];
    __shared__ int   sm;

    const int tile = blockIdx.x;
    const int t    = threadIdx.x;

    // zero accumulators, preload list
    for (int k = t; k < TILE * LPAD; k += 256) lsum[k] = 0.0f;
    if (t < TILE) lcnt[t] = 0;
    if (t == 0)   sm = min(tile_cnt[tile], TCAP);
    if (t < TCAP) slist[t] = tile_list[tile * TCAP + t];
    __syncthreads();

    // load phase: each wave takes points round-robin; lanes span channels.
    // feat read is fully coalesced (256 B per instruction).
    const int wave = t >> 6;
    const int lane = t & 63;
    const int m = sm;
    for (int j = wave; j < m; j += 4) {
        int e    = slist[j];
        int p    = e >> 6;
        int cell = e & 63;
        const float* fp = feat + (size_t)p * Cc;
        float v0 = fp[lane];
        float v1 = fp[lane + 64];
        atomicAdd(&lsum[cell * LPAD + lane],      v0);   // LDS atomics: 2-way banks, free
        atomicAdd(&lsum[cell * LPAD + lane + 64], v1);
        if (lane == 0) atomicAdd(&lcnt[cell], 1);
    }
    __syncthreads();

    if (t < TILE) {
        int n = lcnt[t];
        linv[t] = n > 0 ? 1.0f / (float)n : 0.0f;
    }
    __syncthreads();

    // write phase: lanes span spatial; float4 stores along s (coalesced, 1x).
    const int b  = tile / (Sc / TILE);
    const int s0 = (tile % (Sc / TILE)) * TILE;
    float* ob = out + (size_t)b * Cc * Sc + s0;
    #pragma unroll
    for (int iter = 0; iter < 8; ++iter) {
        int idx = iter * 256 + t;          // 0..2047
        int c   = idx >> 4;                // 0..127
        int sg  = (idx & 15) * 4;          // 0,4,..,60
        float4 o;
        o.x = lsum[(sg + 0) * LPAD + c] * linv[sg + 0];
        o.y = lsum[(sg + 1) * LPAD + c] * linv[sg + 1];
        o.z = lsum[(sg + 2) * LPAD + c] * linv[sg + 2];
        o.w = lsum[(sg + 3) * LPAD + c] * linv[sg + 3];
        *reinterpret_cast<float4*>(ob + (size_t)c * Sc + sg) = o;
    }
}

// ---- fallback (atomic scatter, from R1) ------------------------------------
__global__ void pps_count_kernel(const int* __restrict__ coords,
                                 int* __restrict__ cnt, int N) {
    int i = blockIdx.x * blockDim.x + threadIdx.x;
    if (i >= N) return;
    int4 c = reinterpret_cast<const int4*>(coords)[i];
    int gidx = c.x * Sc + c.y * (NYc * NXc) + c.z * NXc + c.w;
    atomicAdd(&cnt[gidx], 1);
}

__global__ void pps_scatter_kernel(const float* __restrict__ feat,
                                   const int* __restrict__ coords,
                                   const int* __restrict__ cnt,
                                   float* __restrict__ out, int N) {
    int t = blockIdx.x * blockDim.x + threadIdx.x;
    int i = t >> 5;
    int g = t & 31;
    if (i >= N) return;
    int4 c = reinterpret_cast<const int4*>(coords)[i];
    int s    = c.y * (NYc * NXc) + c.z * NXc + c.w;
    int gidx = c.x * Sc + s;
    int n = cnt[gidx];
    float4 v = reinterpret_cast<const float4*>(feat + (size_t)i * Cc)[g];
    float* base = out + ((size_t)c.x * Cc + (size_t)g * 4) * Sc + s;
    if (n == 1) {
        base[0 * (size_t)Sc] = v.x;
        base[1 * (size_t)Sc] = v.y;
        base[2 * (size_t)Sc] = v.z;
        base[3 * (size_t)Sc] = v.w;
    } else {
        float inv = 1.0f / (float)n;
        atomicAdd(&base[0 * (size_t)Sc], v.x * inv);
        atomicAdd(&base[1 * (size_t)Sc], v.y * inv);
        atomicAdd(&base[2 * (size_t)Sc], v.z * inv);
        atomicAdd(&base[3 * (size_t)Sc], v.w * inv);
    }
}

// ---- launch -----------------------------------------------------------------
extern "C" void kernel_launch(void* const* d_in, const int* in_sizes, int n_in,
                              void* d_out, int out_size, void* d_ws, size_t ws_size,
                              hipStream_t stream) {
    const float* feat   = reinterpret_cast<const float*>(d_in[0]);
    const int*   coords = reinterpret_cast<const int*>(d_in[1]);
    float*       out    = reinterpret_cast<float*>(d_out);

    const int N = in_sizes[0] / Cc;  // 160000

    const size_t tcnt_bytes  = (size_t)NTILE * sizeof(int);          // 32.4 KB
    const size_t tlist_bytes = (size_t)NTILE * TCAP * sizeof(int);   // 3.11 MB

    if (ws_size >= tcnt_bytes + tlist_bytes) {
        int* tile_cnt  = reinterpret_cast<int*>(d_ws);
        int* tile_list = reinterpret_cast<int*>((char*)d_ws + tcnt_bytes);
        hipMemsetAsync(d_ws, 0, tcnt_bytes, stream);
        {
            int threads = 256;
            int blocks = (N + threads - 1) / threads;
            pps_fill_tiles<<<blocks, threads, 0, stream>>>(coords, tile_cnt, tile_list, N);
        }
        pps_gather2<<<NTILE, 256, 0, stream>>>(feat, tile_cnt, tile_list, out);
    } else {
        // fallback: atomic scatter
        int* cnt = reinterpret_cast<int*>(d_ws);
        hipMemsetAsync(d_out, 0, (size_t)out_size * sizeof(float), stream);
        hipMemsetAsync(d_ws, 0, (size_t)BSc * sizeof(int), stream);
        {
            int threads = 256;
            int blocks = (N + threads - 1) / threads;
            pps_count_kernel<<<blocks, threads, 0, stream>>>(coords, cnt, N);
        }
        {
            int threads = 256;
            long long total = (long long)N * 32;
            int blocks = (int)((total + threads - 1) / threads);
            pps_scatter_kernel<<<blocks, threads, 0, stream>>>(feat, coords, cnt, out, N);
        }
    }
}

// Round 5
// 147.370 us; speedup vs baseline: 1.1523x; 1.1523x over previous
//
#include <hip/hip_runtime.h>

// PointPillarScatter3d: scatter-mean of pillar features into BEV grid.
// R5 (= R4 with compile fix): tile-binned gather, LDS-staged transpose,
// 512-thread blocks for full occupancy (4 blocks/CU x 8 waves = 32 waves/CU),
// 2-deep load pipelining, nontemporal output stores via native vector type.
// inputs: d_in[0] = pillar_features [N,C] fp32, d_in[1] = voxel_coords [N,4] int32 (b,z,y,x)
// output: bev [B, C, NY, NX] fp32.

typedef float nfloat4 __attribute__((ext_vector_type(4)));  // nontemporal-store-compatible

constexpr int NXc = 360;
constexpr int NYc = 360;
constexpr int NZc = 1;
constexpr int Cc  = 128;
constexpr int Bc  = 4;
constexpr int Sc  = NZc * NYc * NXc;     // 129600 (divisible by 64)
constexpr int BSc = Bc * Sc;             // 518400
constexpr int TILE  = 64;                // cells per tile
constexpr int NTILE = BSc / TILE;        // 8100
constexpr int TCAP  = 96;                // max points/tile (mean 19.75; Poisson tail ~0)
constexpr int LPAD  = Cc + 1;            // padded LDS row stride (bank-conflict-free)

// ---- fill: bin points into tiles -------------------------------------------
__global__ void pps_fill_tiles(const int* __restrict__ coords,
                               int* __restrict__ tile_cnt,
                               int* __restrict__ tile_list, int N) {
    int i = blockIdx.x * blockDim.x + threadIdx.x;
    if (i >= N) return;
    int4 c = reinterpret_cast<const int4*>(coords)[i];          // (b,z,y,x)
    int gidx = c.x * Sc + c.y * (NYc * NXc) + c.z * NXc + c.w;  // 0..BSc-1
    int tile = gidx >> 6;                                       // TILE=64
    int cell = gidx & 63;
    int slot = atomicAdd(&tile_cnt[tile], 1);
    if (slot < TCAP) tile_list[tile * TCAP + slot] = (i << 6) | cell;
}

// ---- gather: one block (512 thr) per 64-cell tile ---------------------------
__global__ __launch_bounds__(512)
void pps_gather3(const float* __restrict__ feat,
                 const int* __restrict__ tile_cnt,
                 const int* __restrict__ tile_list,
                 float* __restrict__ out) {
    __shared__ float lsum[TILE * LPAD];   // 33 KB accumulation tile
    __shared__ float linv[TILE];
    __shared__ int   lcnt[TILE];
    __shared__ int   slist[TCAP];
    __shared__ int   sm;

    const int tile = blockIdx.x;
    const int t    = threadIdx.x;

    // zero accumulators, preload list
    for (int k = t; k < TILE * LPAD; k += 512) lsum[k] = 0.0f;
    if (t < TILE) lcnt[t] = 0;
    if (t == 0)   sm = min(tile_cnt[tile], TCAP);
    if (t < TCAP) slist[t] = tile_list[tile * TCAP + t];
    __syncthreads();

    // load phase: wave per point, lanes span channels (coalesced 256B loads).
    // 2-deep pipelining: both points' global loads issue before any atomic.
    const int wave = t >> 6;              // 0..7
    const int lane = t & 63;
    const int m = sm;
    for (int j = wave; j < m; j += 16) {
        int e0 = slist[j];
        int j1 = j + 8;
        bool h1 = j1 < m;
        int e1 = h1 ? slist[j1] : e0;
        int p0 = e0 >> 6, cell0 = e0 & 63;
        int p1 = e1 >> 6, cell1 = e1 & 63;
        const float* f0 = feat + (size_t)p0 * Cc;
        const float* f1 = feat + (size_t)p1 * Cc;
        float a0 = f0[lane];
        float a1 = f0[lane + 64];
        float b0 = f1[lane];
        float b1 = f1[lane + 64];
        atomicAdd(&lsum[cell0 * LPAD + lane],      a0);   // banks: lane mod 32 -> 2-way (free)
        atomicAdd(&lsum[cell0 * LPAD + lane + 64], a1);
        if (lane == 0) atomicAdd(&lcnt[cell0], 1);
        if (h1) {
            atomicAdd(&lsum[cell1 * LPAD + lane],      b0);
            atomicAdd(&lsum[cell1 * LPAD + lane + 64], b1);
            if (lane == 0) atomicAdd(&lcnt[cell1], 1);
        }
    }
    __syncthreads();

    if (t < TILE) {
        int n = lcnt[t];
        linv[t] = n > 0 ? 1.0f / (float)n : 0.0f;
    }
    __syncthreads();

    // write phase: lanes span spatial; nontemporal float4 stores along s.
    const int b  = tile / (Sc / TILE);
    const int s0 = (tile % (Sc / TILE)) * TILE;
    float* ob = out + (size_t)b * Cc * Sc + s0;
    #pragma unroll
    for (int iter = 0; iter < 4; ++iter) {
        int idx = iter * 512 + t;          // 0..2047
        int c   = idx >> 4;                // 0..127
        int sg  = (idx & 15) * 4;          // 0,4,..,60
        nfloat4 o;
        o.x = lsum[(sg + 0) * LPAD + c] * linv[sg + 0];
        o.y = lsum[(sg + 1) * LPAD + c] * linv[sg + 1];
        o.z = lsum[(sg + 2) * LPAD + c] * linv[sg + 2];
        o.w = lsum[(sg + 3) * LPAD + c] * linv[sg + 3];
        __builtin_nontemporal_store(o, reinterpret_cast<nfloat4*>(ob + (size_t)c * Sc + sg));
    }
}

// ---- fallback (atomic scatter, from R1) ------------------------------------
__global__ void pps_count_kernel(const int* __restrict__ coords,
                                 int* __restrict__ cnt, int N) {
    int i = blockIdx.x * blockDim.x + threadIdx.x;
    if (i >= N) return;
    int4 c = reinterpret_cast<const int4*>(coords)[i];
    int gidx = c.x * Sc + c.y * (NYc * NXc) + c.z * NXc + c.w;
    atomicAdd(&cnt[gidx], 1);
}

__global__ void pps_scatter_kernel(const float* __restrict__ feat,
                                   const int* __restrict__ coords,
                                   const int* __restrict__ cnt,
                                   float* __restrict__ out, int N) {
    int t = blockIdx.x * blockDim.x + threadIdx.x;
    int i = t >> 5;
    int g = t & 31;
    if (i >= N) return;
    int4 c = reinterpret_cast<const int4*>(coords)[i];
    int s    = c.y * (NYc * NXc) + c.z * NXc + c.w;
    int gidx = c.x * Sc + s;
    int n = cnt[gidx];
    float4 v = reinterpret_cast<const float4*>(feat + (size_t)i * Cc)[g];
    float* base = out + ((size_t)c.x * Cc + (size_t)g * 4) * Sc + s;
    if (n == 1) {
        base[0 * (size_t)Sc] = v.x;
        base[1 * (size_t)Sc] = v.y;
        base[2 * (size_t)Sc] = v.z;
        base[3 * (size_t)Sc] = v.w;
    } else {
        float inv = 1.0f / (float)n;
        atomicAdd(&base[0 * (size_t)Sc], v.x * inv);
        atomicAdd(&base[1 * (size_t)Sc], v.y * inv);
        atomicAdd(&base[2 * (size_t)Sc], v.z * inv);
        atomicAdd(&base[3 * (size_t)Sc], v.w * inv);
    }
}

// ---- launch -----------------------------------------------------------------
extern "C" void kernel_launch(void* const* d_in, const int* in_sizes, int n_in,
                              void* d_out, int out_size, void* d_ws, size_t ws_size,
                              hipStream_t stream) {
    const float* feat   = reinterpret_cast<const float*>(d_in[0]);
    const int*   coords = reinterpret_cast<const int*>(d_in[1]);
    float*       out    = reinterpret_cast<float*>(d_out);

    const int N = in_sizes[0] / Cc;  // 160000

    const size_t tcnt_bytes  = (size_t)NTILE * sizeof(int);          // 32.4 KB
    const size_t tlist_bytes = (size_t)NTILE * TCAP * sizeof(int);   // 3.11 MB

    if (ws_size >= tcnt_bytes + tlist_bytes) {
        int* tile_cnt  = reinterpret_cast<int*>(d_ws);
        int* tile_list = reinterpret_cast<int*>((char*)d_ws + tcnt_bytes);
        (void)hipMemsetAsync(d_ws, 0, tcnt_bytes, stream);
        {
            int threads = 256;
            int blocks = (N + threads - 1) / threads;
            pps_fill_tiles<<<blocks, threads, 0, stream>>>(coords, tile_cnt, tile_list, N);
        }
        pps_gather3<<<NTILE, 512, 0, stream>>>(feat, tile_cnt, tile_list, out);
    } else {
        // fallback: atomic scatter
        int* cnt = reinterpret_cast<int*>(d_ws);
        (void)hipMemsetAsync(d_out, 0, (size_t)out_size * sizeof(float), stream);
        (void)hipMemsetAsync(d_ws, 0, (size_t)BSc * sizeof(int), stream);
        {
            int threads = 256;
            int blocks = (N + threads - 1) / threads;
            pps_count_kernel<<<blocks, threads, 0, stream>>>(coords, cnt, N);
        }
        {
            int threads = 256;
            long long total = (long long)N * 32;
            int blocks = (int)((total + threads - 1) / threads);
            pps_scatter_kernel<<<blocks, threads, 0, stream>>>(feat, coords, cnt, out, N);
        }
    }
}